// Round 16
// baseline (604.568 us; speedup 1.0000x reference)
//
#include <hip/hip_runtime.h>
#include <stdint.h>

typedef __attribute__((ext_vector_type(8))) short short8;
typedef __attribute__((ext_vector_type(4))) float f32x4;

static __device__ __forceinline__ uint16_t f2bf(float f) {
  uint32_t u = __builtin_bit_cast(uint32_t, f);
  u += 0x7FFFu + ((u >> 16) & 1u);
  return (uint16_t)(u >> 16);
}

// ---------- utilities ----------
__global__ __launch_bounds__(256) void k_zeroi(int* __restrict__ p, int n) {
  int i = blockIdx.x * 256 + threadIdx.x;
  if (i < n) p[i] = 0;
}
__global__ __launch_bounds__(256) void k_copyi(const int* __restrict__ a,
                                               int* __restrict__ b, int n) {
  int i = blockIdx.x * 256 + threadIdx.x;
  if (i < n) b[i] = a[i];
}

// ---------- index dtype detection + conversion ----------
__global__ __launch_bounds__(256) void k_detect(const long long* ei64, int n64,
                                                long long nmax, int* flag) {
  __shared__ int ok;
  if (threadIdx.x == 0) ok = 1;
  __syncthreads();
  for (int i = threadIdx.x; i < n64; i += 256) {
    long long v = ei64[i];
    if (v < 0 || v >= nmax) atomicAnd(&ok, 0);
  }
  __syncthreads();
  if (threadIdx.x == 0) *flag = ok;
}

__global__ __launch_bounds__(256) void k_convert(const void* ei, int e2,
                                                 const int* __restrict__ flag,
                                                 int* __restrict__ out) {
  int i = blockIdx.x * 256 + threadIdx.x;
  if (i >= e2) return;
  out[i] = (*flag) ? (int)((const long long*)ei)[i] : ((const int*)ei)[i];
}

// ---------- counting sort by dst ----------
__global__ __launch_bounds__(256) void k_count(const int* __restrict__ dst, int E,
                                               int* __restrict__ cnt) {
  int i = blockIdx.x * 256 + threadIdx.x;
  if (i < E) atomicAdd(&cnt[dst[i]], 1);
}

__global__ __launch_bounds__(256) void k_scan1(const int* __restrict__ cnt, int n,
                                               int* __restrict__ excl,
                                               int* __restrict__ bsum) {
  __shared__ int s[256];
  int i = blockIdx.x * 256 + threadIdx.x;
  int v = (i < n) ? cnt[i] : 0;
  s[threadIdx.x] = v;
  __syncthreads();
  #pragma unroll
  for (int off = 1; off < 256; off <<= 1) {
    int t = (threadIdx.x >= off) ? s[threadIdx.x - off] : 0;
    __syncthreads();
    s[threadIdx.x] += t;
    __syncthreads();
  }
  if (i < n) excl[i] = s[threadIdx.x] - v;
  if (threadIdx.x == 255) bsum[blockIdx.x] = s[255];
}
__global__ void k_scan2(int* bsum, int nb) {
  if (threadIdx.x == 0 && blockIdx.x == 0) {
    int run = 0;
    for (int b = 0; b < nb; ++b) { int t = bsum[b]; bsum[b] = run; run += t; }
  }
}
__global__ __launch_bounds__(256) void k_scan3(int* __restrict__ excl,
                                               const int* __restrict__ bsum,
                                               int n, int E) {
  int i = blockIdx.x * 256 + threadIdx.x;
  if (i < n) excl[i] += bsum[blockIdx.x];
  if (i == 0) excl[n] = E;
}

__global__ __launch_bounds__(256) void k_scatter(const int* __restrict__ src,
                                                 const int* __restrict__ dst, int E,
                                                 int* __restrict__ rowcur,
                                                 int* __restrict__ eid,
                                                 int* __restrict__ srcS) {
  int e = blockIdx.x * 256 + threadIdx.x;
  if (e >= E) return;
  int d = dst[e];
  int pos = atomicAdd(&rowcur[d], 1);
  eid[pos] = e;
  srcS[pos] = src[e];
}

// ---------- weight pre-tiling into MFMA fragment order (r4 layout) ----------
// Also emits w1t: k-major layer-1 weights, 8-padded per k:
//   w1t[k*8 + r] = k1w[r][k] for r<6, = k1b[k] for r==6, = 0 for r==7.
__global__ __launch_bounds__(256) void k_prep(const float* __restrict__ k2w,
                                              const float* __restrict__ k3w,
                                              const float* __restrict__ k1w,
                                              const float* __restrict__ k1b,
                                              uint16_t* __restrict__ w2t,
                                              uint16_t* __restrict__ w3t,
                                              float* __restrict__ w1t) {
  int d = blockIdx.x * 256 + threadIdx.x;
  int tile = d >> 9, ww = d & 511;
  int m16 = ww >> 5, q4 = (ww >> 3) & 3, jj = ww & 7;
  int ot = tile >> 2, kst = tile & 3;
  int k = kst * 32 + q4 * 8 + jj;
  if (d < 16384) {
    int j = ot * 16 + m16;
    w2t[d] = f2bf(k2w[k * 128 + j]);
  }
  if (d < 32768) {
    int oc = ot * 16 + m16;
    w3t[d] = f2bf(k3w[k * 256 + oc]);
  }
  if (d < 1024) {
    int kk = d >> 3, r = d & 7;
    w1t[d] = (r < 6) ? k1w[r * 128 + kk] : ((r == 6) ? k1b[kk] : 0.0f);
  }
}

// ---------- feat0 = x @ fc1_w + fc1_b ----------
__global__ __launch_bounds__(256) void k_feat0(const float* __restrict__ x,
                                               const float* __restrict__ w,
                                               const float* __restrict__ b,
                                               float* __restrict__ feat, int N) {
  int n = blockIdx.x * 256 + threadIdx.x;
  if (n >= N) return;
  float xv = x[n];
  float4* fp = (float4*)(feat + (size_t)n * 16);
  #pragma unroll
  for (int q = 0; q < 4; ++q) {
    float4 v;
    v.x = xv * w[q*4+0] + b[q*4+0];
    v.y = xv * w[q*4+1] + b[q*4+1];
    v.z = xv * w[q*4+2] + b[q*4+2];
    v.w = xv * w[q*4+3] + b[q*4+3];
    fp[q] = v;
  }
}

// ---------- edge MLP layers 1+2 v4: b128 weight reads, shared across et ----------
// 512 threads = 8 waves; wave covers 2 tiles x 16 edges. Layer-1 weights for each k
// loaded once as 2x float4 (bias folded into slot 6), shared by both et -> LDS reads
// per thread drop 384 b32 -> 64 b128. Accumulation order preserved (bias first,
// then a0..a5) -> bit-identical to r15. Layer-2 sweep/store byte-identical to r15.
__global__ __launch_bounds__(512) void k_mlp12(
    const float* __restrict__ ea, const int* __restrict__ eid,
    const float* __restrict__ w1t,
    const uint16_t* __restrict__ w2t, const float* __restrict__ k2b,
    uint16_t* __restrict__ h2, int e0, int e1) {
  __shared__ uint16_t s_w2[16384];   // 32KB, lane-linear in-tile order
  __shared__ float s_k1t[1024];      // 4KB, k-major 8-padded (w + bias)
  __shared__ float s_b2[128];
  int tid = threadIdx.x;
  #pragma unroll
  for (int it = 0; it < 4; ++it) {   // 4 x 512 = 2048 uint4 = full 32KB tile
    int g = it * 512 + tid;
    int tile = g >> 6, o8 = g & 63;
    ((uint4*)s_w2)[tile * 64 + (o8 & 3) * 16 + (o8 >> 2)] = ((const uint4*)w2t)[g];
  }
  for (int i = tid; i < 1024; i += 512) s_k1t[i] = w1t[i];
  if (tid < 128) s_b2[tid] = k2b[tid];
  __syncthreads();

  int w = tid >> 6, lane = tid & 63;
  int m16 = lane & 15, q4 = lane >> 4;
  int wbase = e0 + blockIdx.x * 256 + w * 32;

  // hoisted ea for the wave's 2 edges-per-lane
  float a[2][6];
  #pragma unroll
  for (int et = 0; et < 2; ++et) {
    int i = wbase + et*16 + m16;
    int ic = i < e1 ? i : e1 - 1;
    int es = eid[ic];
    const float* ap = ea + (size_t)es * 6;
    a[et][0] = ap[0]; a[et][1] = ap[1]; a[et][2] = ap[2];
    a[et][3] = ap[3]; a[et][4] = ap[4]; a[et][5] = ap[5];
  }

  // layer 1: per (kst,jj) one weight load pair feeds both et
  short8 Y[2][4];
  #pragma unroll
  for (int kst = 0; kst < 4; ++kst) {
    float v[2][8];
    #pragma unroll
    for (int jj = 0; jj < 8; ++jj) {
      int k = kst*32 + q4*8 + jj;
      float4 wa = *(const float4*)&s_k1t[k*8];
      float4 wb = *(const float4*)&s_k1t[k*8 + 4];
      #pragma unroll
      for (int et = 0; et < 2; ++et) {
        float t = wb.z + a[et][0]*wa.x + a[et][1]*wa.y + a[et][2]*wa.z
                + a[et][3]*wa.w + a[et][4]*wb.x + a[et][5]*wb.y;
        v[et][jj] = fmaxf(t, 0.0f);
      }
    }
    #pragma unroll
    for (int et = 0; et < 2; ++et) {
      short8 y;
      #pragma unroll
      for (int jj = 0; jj < 8; ++jj) y[jj] = (short)f2bf(v[et][jj]);
      Y[et][kst] = y;
    }
  }

  // layer 2 + store: exact r15 structure per et
  #pragma unroll
  for (int et = 0; et < 2; ++et) {
    int i0 = wbase + et * 16;
    int i = i0 + m16;

    f32x4 acc[8];
    #pragma unroll
    for (int jt = 0; jt < 8; ++jt) acc[jt] = f32x4{0.f,0.f,0.f,0.f};
    #pragma unroll
    for (int kst = 0; kst < 4; ++kst) {
      #pragma unroll
      for (int jt = 0; jt < 8; ++jt) {
        short8 X = *(const short8*)&s_w2[(jt*4 + kst)*512 + lane*8];
        acc[jt] = __builtin_amdgcn_mfma_f32_16x16x32_bf16(X, Y[et][kst], acc[jt], 0, 0, 0);
      }
    }

    if (i < e1) {
      size_t hb = (size_t)((i0 - e0) >> 4) * 2048;
      #pragma unroll
      for (int jt = 0; jt < 8; ++jt) {
        int jb = jt*16 + q4*4;
        float v0 = fmaxf(acc[jt][0] + s_b2[jb+0], 0.0f);
        float v1 = fmaxf(acc[jt][1] + s_b2[jb+1], 0.0f);
        float v2 = fmaxf(acc[jt][2] + s_b2[jb+2], 0.0f);
        float v3 = fmaxf(acc[jt][3] + s_b2[jb+3], 0.0f);
        uint2 pk;
        pk.x = ((uint32_t)f2bf(v1) << 16) | f2bf(v0);
        pk.y = ((uint32_t)f2bf(v3) << 16) | f2bf(v2);
        size_t off = hb + (size_t)(((jt*2 + (q4>>1))*16 + m16)*8 + (q4&1)*4);
        *(uint2*)&h2[off] = pk;
      }
    }
  }
}

// ---------- fused v7 (r12/r15, unchanged): 512 threads = 8 waves ----------
__global__ __launch_bounds__(512) void k_fused(
    const uint16_t* __restrict__ h2, const uint16_t* __restrict__ w3t,
    const float* __restrict__ k3b, const float* __restrict__ feat,
    const int* __restrict__ srcS, float* __restrict__ msg, int e0, int e1) {
  __shared__ uint16_t s_w3[32768];   // 64KB = 4096 uint4; 8 iters x 512 = 4096 ✓
  __shared__ float s_b3[256];
  int tid = threadIdx.x;
  #pragma unroll
  for (int it = 0; it < 8; ++it) {
    int g = it * 512 + tid;
    int tile = g >> 6, o8 = g & 63;
    ((uint4*)s_w3)[tile * 64 + (o8 & 3) * 16 + (o8 >> 2)] = ((const uint4*)w3t)[g];
  }
  if (tid < 256) s_b3[tid] = k3b[tid];
  __syncthreads();

  int w = tid >> 6, lane = tid & 63;
  int m16 = lane & 15, q4 = lane >> 4;
  int wbase = e0 + blockIdx.x * 256 + w * 32;
  int maxt = (e1 - 1 - e0) >> 4;

  // Y fragments for both tiles (coalesced 1KB-per-kst global reads)
  short8 Y[2][4];
  #pragma unroll
  for (int et = 0; et < 2; ++et) {
    int t = ((wbase - e0) >> 4) + et; if (t > maxt) t = maxt;
    const uint16_t* hb = h2 + (size_t)t * 2048;
    #pragma unroll
    for (int kst = 0; kst < 4; ++kst)
      Y[et][kst] = *(const short8*)&hb[(size_t)((kst*4 + q4)*16 + m16)*8];
  }

  // feat gather for both edges
  float f[2][16];
  #pragma unroll
  for (int et = 0; et < 2; ++et) {
    int i = wbase + et*16 + m16;
    int ic = i < e1 ? i : e1 - 1;
    int s = srcS[ic];
    const float4* fp = (const float4*)(feat + (size_t)s * 16);
    #pragma unroll
    for (int q = 0; q < 4; ++q) {
      float4 t = fp[q];
      f[et][q*4] = t.x; f[et][q*4+1] = t.y; f[et][q*4+2] = t.z; f[et][q*4+3] = t.w;
    }
  }

  // MFMA sweep: one X read feeds both tiles; all 32 accumulators stay live.
  f32x4 acc[2][16];
  #pragma unroll
  for (int et = 0; et < 2; ++et)
    #pragma unroll
    for (int t = 0; t < 16; ++t) acc[et][t] = f32x4{0.f,0.f,0.f,0.f};
  #pragma unroll
  for (int kst = 0; kst < 4; ++kst) {
    #pragma unroll
    for (int oct = 0; oct < 16; ++oct) {
      short8 X = *(const short8*)&s_w3[(oct*4 + kst)*512 + lane*8];
      acc[0][oct] = __builtin_amdgcn_mfma_f32_16x16x32_bf16(X, Y[0][kst], acc[0][oct], 0, 0, 0);
      acc[1][oct] = __builtin_amdgcn_mfma_f32_16x16x32_bf16(X, Y[1][kst], acc[1][oct], 0, 0, 0);
    }
  }

  // fold + store (after all MFMAs — invariant)
  #pragma unroll
  for (int et = 0; et < 2; ++et) {
    float4 m = {0.f, 0.f, 0.f, 0.f};
    #pragma unroll
    for (int ii = 0; ii < 16; ++ii) {
      float4 bv = *(const float4*)&s_b3[ii*16 + q4*4];
      float fi = f[et][ii];
      m.x += fi * (acc[et][ii][0] + bv.x);
      m.y += fi * (acc[et][ii][1] + bv.y);
      m.z += fi * (acc[et][ii][2] + bv.z);
      m.w += fi * (acc[et][ii][3] + bv.w);
    }
    int i = wbase + et*16 + m16;
    if (i < e1) *(float4*)(msg + (size_t)i * 16 + q4 * 4) = m;
  }
}

// ---------- segment-sum + node update fused ----------
__global__ __launch_bounds__(256) void k_agg(
    const float* __restrict__ msg, const int* __restrict__ rowptr,
    const float* __restrict__ fin, const float* __restrict__ rootw,
    const float* __restrict__ convb, float* __restrict__ fout, int N) {
  __shared__ float s_rw[256];
  __shared__ float s_cb[16];
  int tid = threadIdx.x;
  s_rw[tid] = rootw[tid];
  if (tid < 16) s_cb[tid] = convb[tid];
  __syncthreads();
  int n = blockIdx.x * 16 + (tid >> 4);
  int ch = tid & 15;
  if (n >= N) return;
  int p0 = rowptr[n], p1 = rowptr[n+1];
  float sum = 0.0f;
  for (int p = p0; p < p1; ++p) sum += msg[(size_t)p * 16 + ch];
  float di = 1.0f / fmaxf((float)(p1 - p0), 1.0f);
  float o = s_cb[ch] + sum * di;
  const float* fp = fin + (size_t)n * 16;
  #pragma unroll
  for (int i = 0; i < 16; ++i) o += fp[i] * s_rw[i*16 + ch];
  fout[(size_t)n * 16 + ch] = fmaxf(o, 0.0f);
}

// ---------- head ----------
__global__ __launch_bounds__(256) void k_out(const float* __restrict__ feat,
                                             const float* __restrict__ w,
                                             const float* __restrict__ b,
                                             float* __restrict__ out, int N) {
  int n = blockIdx.x * 256 + threadIdx.x;
  if (n >= N) return;
  const float4* fp = (const float4*)(feat + (size_t)n*16);
  float acc = b[0];
  #pragma unroll
  for (int q = 0; q < 4; ++q) {
    float4 t = fp[q];
    acc += t.x*w[q*4] + t.y*w[q*4+1] + t.z*w[q*4+2] + t.w*w[q*4+3];
  }
  out[n] = acc;
}

extern "C" void kernel_launch(void* const* d_in, const int* in_sizes, int n_in,
                              void* d_out, int out_size, void* d_ws, size_t ws_size,
                              hipStream_t stream) {
  const float* x     = (const float*)d_in[0];
  const void*  ei    = d_in[1];
  const float* ea    = (const float*)d_in[2];
  const float* fc1w  = (const float*)d_in[3];
  const float* fc1b  = (const float*)d_in[4];
  const float* k1w   = (const float*)d_in[5];
  const float* k1b   = (const float*)d_in[6];
  const float* k2w   = (const float*)d_in[7];
  const float* k2b   = (const float*)d_in[8];
  const float* k3w   = (const float*)d_in[9];
  const float* k3b   = (const float*)d_in[10];
  const float* rootw = (const float*)d_in[11];
  const float* convb = (const float*)d_in[12];
  const float* fc2w  = (const float*)d_in[13];
  const float* fc2b  = (const float*)d_in[14];
  int N = in_sizes[0];
  int E = in_sizes[1] / 2;

  char* base = (char*)d_ws;
  size_t off = 0;
  auto alloc = [&](size_t bytes) -> void* {
    void* p = base + off;
    off = (off + bytes + 255) & ~(size_t)255;
    return p;
  };
  int*      idx    = (int*)alloc((size_t)2*E*sizeof(int));
  int*      flag   = (int*)alloc(256);
  int*      rowptr = (int*)alloc((size_t)(N+1)*sizeof(int));
  int*      rowcur = (int*)alloc((size_t)N*sizeof(int));
  int*      bsum   = (int*)alloc(1024*sizeof(int));
  int*      eid    = (int*)alloc((size_t)E*sizeof(int));
  int*      srcS   = (int*)alloc((size_t)E*sizeof(int));
  float*    fA     = (float*)alloc((size_t)N*16*sizeof(float));
  float*    fB     = (float*)alloc((size_t)N*16*sizeof(float));
  float*    msg    = (float*)alloc((size_t)E*16*sizeof(float));
  uint16_t* w2t    = (uint16_t*)alloc(16384*2);
  uint16_t* w3t    = (uint16_t*)alloc(32768*2);
  float*    w1t    = (float*)alloc(1024*sizeof(float));
  if (off > ws_size) return;

  long long avail = (long long)ws_size - (long long)off;
  long long fullBytes = (long long)E * 256;
  int chunkE;
  if (avail >= fullBytes) {
    chunkE = E;
  } else {
    chunkE = (int)((avail / 256) & ~511LL);
    if (chunkE < 512) chunkE = 512;
  }
  uint16_t* h2 = (uint16_t*)alloc((size_t)chunkE * 256);
  bool full = (chunkE >= E);

  int* srcI = idx;
  int* dstI = idx + E;

  int n64 = E < 1024 ? E : 1024;
  k_detect<<<1, 256, 0, stream>>>((const long long*)ei, n64, (long long)N, flag);
  k_convert<<<(2*E + 255)/256, 256, 0, stream>>>(ei, 2*E, flag, idx);

  int nbN = (N + 255) / 256;
  k_zeroi<<<nbN, 256, 0, stream>>>(rowcur, N);
  k_count<<<(E + 255)/256, 256, 0, stream>>>(dstI, E, rowcur);
  k_scan1<<<nbN, 256, 0, stream>>>(rowcur, N, rowptr, bsum);
  k_scan2<<<1, 64, 0, stream>>>(bsum, nbN);
  k_scan3<<<nbN, 256, 0, stream>>>(rowptr, bsum, N, E);
  k_copyi<<<nbN, 256, 0, stream>>>(rowptr, rowcur, N);
  k_scatter<<<(E + 255)/256, 256, 0, stream>>>(srcI, dstI, E, rowcur, eid, srcS);

  k_prep<<<128, 256, 0, stream>>>(k2w, k3w, k1w, k1b, w2t, w3t, w1t);
  k_feat0<<<(N + 255)/256, 256, 0, stream>>>(x, fc1w, fc1b, fA, N);
  if (full)
    k_mlp12<<<(E + 255)/256, 512, 0, stream>>>(ea, eid, w1t, w2t, k2b, h2, 0, E);

  float* fin = fA;
  float* fout = fB;
  int nbAgg = (N + 15) / 16;
  for (int d = 0; d < 4; ++d) {
    if (full) {
      k_fused<<<(E + 255)/256, 512, 0, stream>>>(h2, w3t, k3b, fin, srcS, msg, 0, E);
    } else {
      for (int i0 = 0; i0 < E; i0 += chunkE) {
        int i1 = i0 + chunkE < E ? i0 + chunkE : E;
        k_mlp12<<<(i1 - i0 + 255)/256, 512, 0, stream>>>(ea, eid, w1t, w2t, k2b, h2, i0, i1);
        k_fused<<<(i1 - i0 + 255)/256, 512, 0, stream>>>(h2, w3t, k3b, fin, srcS, msg, i0, i1);
      }
    }
    k_agg<<<nbAgg, 256, 0, stream>>>(msg, rowptr, fin, rootw, convb, fout, N);
    float* t = fin; fin = fout; fout = t;
  }
  k_out<<<(N + 255)/256, 256, 0, stream>>>(fin, fc2w, fc2b, (float*)d_out, N);
}

// Round 17
// 386.614 us; speedup vs baseline: 1.5638x; 1.5638x over previous
//
#include <hip/hip_runtime.h>
#include <stdint.h>

typedef __attribute__((ext_vector_type(8))) short short8;
typedef __attribute__((ext_vector_type(4))) float f32x4;

static __device__ __forceinline__ uint16_t f2bf(float f) {
  uint32_t u = __builtin_bit_cast(uint32_t, f);
  u += 0x7FFFu + ((u >> 16) & 1u);
  return (uint16_t)(u >> 16);
}

// ---------- utilities ----------
__global__ __launch_bounds__(256) void k_zeroi(int* __restrict__ p, int n) {
  int i = blockIdx.x * 256 + threadIdx.x;
  if (i < n) p[i] = 0;
}
__global__ __launch_bounds__(256) void k_copyi(const int* __restrict__ a,
                                               int* __restrict__ b, int n) {
  int i = blockIdx.x * 256 + threadIdx.x;
  if (i < n) b[i] = a[i];
}

// ---------- index dtype detection + conversion ----------
__global__ __launch_bounds__(256) void k_detect(const long long* ei64, int n64,
                                                long long nmax, int* flag) {
  __shared__ int ok;
  if (threadIdx.x == 0) ok = 1;
  __syncthreads();
  for (int i = threadIdx.x; i < n64; i += 256) {
    long long v = ei64[i];
    if (v < 0 || v >= nmax) atomicAnd(&ok, 0);
  }
  __syncthreads();
  if (threadIdx.x == 0) *flag = ok;
}

__global__ __launch_bounds__(256) void k_convert(const void* ei, int e2,
                                                 const int* __restrict__ flag,
                                                 int* __restrict__ out) {
  int i = blockIdx.x * 256 + threadIdx.x;
  if (i >= e2) return;
  out[i] = (*flag) ? (int)((const long long*)ei)[i] : ((const int*)ei)[i];
}

// ---------- counting sort by dst ----------
__global__ __launch_bounds__(256) void k_count(const int* __restrict__ dst, int E,
                                               int* __restrict__ cnt) {
  int i = blockIdx.x * 256 + threadIdx.x;
  if (i < E) atomicAdd(&cnt[dst[i]], 1);
}

__global__ __launch_bounds__(256) void k_scan1(const int* __restrict__ cnt, int n,
                                               int* __restrict__ excl,
                                               int* __restrict__ bsum) {
  __shared__ int s[256];
  int i = blockIdx.x * 256 + threadIdx.x;
  int v = (i < n) ? cnt[i] : 0;
  s[threadIdx.x] = v;
  __syncthreads();
  #pragma unroll
  for (int off = 1; off < 256; off <<= 1) {
    int t = (threadIdx.x >= off) ? s[threadIdx.x - off] : 0;
    __syncthreads();
    s[threadIdx.x] += t;
    __syncthreads();
  }
  if (i < n) excl[i] = s[threadIdx.x] - v;
  if (threadIdx.x == 255) bsum[blockIdx.x] = s[255];
}
__global__ void k_scan2(int* bsum, int nb) {
  if (threadIdx.x == 0 && blockIdx.x == 0) {
    int run = 0;
    for (int b = 0; b < nb; ++b) { int t = bsum[b]; bsum[b] = run; run += t; }
  }
}
__global__ __launch_bounds__(256) void k_scan3(int* __restrict__ excl,
                                               const int* __restrict__ bsum,
                                               int n, int E) {
  int i = blockIdx.x * 256 + threadIdx.x;
  if (i < n) excl[i] += bsum[blockIdx.x];
  if (i == 0) excl[n] = E;
}

__global__ __launch_bounds__(256) void k_scatter(const int* __restrict__ src,
                                                 const int* __restrict__ dst, int E,
                                                 int* __restrict__ rowcur,
                                                 int* __restrict__ eid,
                                                 int* __restrict__ srcS) {
  int e = blockIdx.x * 256 + threadIdx.x;
  if (e >= E) return;
  int d = dst[e];
  int pos = atomicAdd(&rowcur[d], 1);
  eid[pos] = e;
  srcS[pos] = src[e];
}

// ---------- weight pre-tiling into MFMA fragment order (r4 layout) ----------
// Also emits w1t: k-major layer-1 weights, 8-padded per k:
//   w1t[k*8 + r] = k1w[r][k] for r<6, = k1b[k] for r==6, = 0 for r==7.
__global__ __launch_bounds__(256) void k_prep(const float* __restrict__ k2w,
                                              const float* __restrict__ k3w,
                                              const float* __restrict__ k1w,
                                              const float* __restrict__ k1b,
                                              uint16_t* __restrict__ w2t,
                                              uint16_t* __restrict__ w3t,
                                              float* __restrict__ w1t) {
  int d = blockIdx.x * 256 + threadIdx.x;
  int tile = d >> 9, ww = d & 511;
  int m16 = ww >> 5, q4 = (ww >> 3) & 3, jj = ww & 7;
  int ot = tile >> 2, kst = tile & 3;
  int k = kst * 32 + q4 * 8 + jj;
  if (d < 16384) {
    int j = ot * 16 + m16;
    w2t[d] = f2bf(k2w[k * 128 + j]);
  }
  if (d < 32768) {
    int oc = ot * 16 + m16;
    w3t[d] = f2bf(k3w[k * 256 + oc]);
  }
  if (d < 1024) {
    int kk = d >> 3, r = d & 7;
    w1t[d] = (r < 6) ? k1w[r * 128 + kk] : ((r == 6) ? k1b[kk] : 0.0f);
  }
}

// ---------- feat0 = x @ fc1_w + fc1_b ----------
__global__ __launch_bounds__(256) void k_feat0(const float* __restrict__ x,
                                               const float* __restrict__ w,
                                               const float* __restrict__ b,
                                               float* __restrict__ feat, int N) {
  int n = blockIdx.x * 256 + threadIdx.x;
  if (n >= N) return;
  float xv = x[n];
  float4* fp = (float4*)(feat + (size_t)n * 16);
  #pragma unroll
  for (int q = 0; q < 4; ++q) {
    float4 v;
    v.x = xv * w[q*4+0] + b[q*4+0];
    v.y = xv * w[q*4+1] + b[q*4+1];
    v.z = xv * w[q*4+2] + b[q*4+2];
    v.w = xv * w[q*4+3] + b[q*4+3];
    fp[q] = v;
  }
}

// ---------- edge MLP layers 1+2 v5: r15 per-et serial body + b128 weight reads ----------
// 512 threads = 8 waves; wave covers 2 tiles x 16 edges. EXACT r15 structure (per-et
// serial, low live-set — r13/r16 both spilled by hoisting state across et). Only the
// layer-1 weight READ changed: per k, 2x float4 from k-major 8-padded w1t (bias in
// slot 6), 16-lane broadcast per phase -> conflict-free. 384 b32 -> 128 b128 reads.
__global__ __launch_bounds__(512) void k_mlp12(
    const float* __restrict__ ea, const int* __restrict__ eid,
    const float* __restrict__ w1t,
    const uint16_t* __restrict__ w2t, const float* __restrict__ k2b,
    uint16_t* __restrict__ h2, int e0, int e1) {
  __shared__ uint16_t s_w2[16384];   // 32KB, lane-linear in-tile order
  __shared__ float s_k1t[1024];      // 4KB, k-major 8-padded (w + bias)
  __shared__ float s_b2[128];
  int tid = threadIdx.x;
  #pragma unroll
  for (int it = 0; it < 4; ++it) {   // 4 x 512 = 2048 uint4 = full 32KB tile
    int g = it * 512 + tid;
    int tile = g >> 6, o8 = g & 63;
    ((uint4*)s_w2)[tile * 64 + (o8 & 3) * 16 + (o8 >> 2)] = ((const uint4*)w2t)[g];
  }
  for (int i = tid; i < 1024; i += 512) s_k1t[i] = w1t[i];
  if (tid < 128) s_b2[tid] = k2b[tid];
  __syncthreads();

  int w = tid >> 6, lane = tid & 63;
  int m16 = lane & 15, q4 = lane >> 4;
  int wbase = e0 + blockIdx.x * 256 + w * 32;

  #pragma unroll
  for (int et = 0; et < 2; ++et) {
    int i0 = wbase + et * 16;
    int i = i0 + m16;
    int ic = i < e1 ? i : e1 - 1;
    int es = eid[ic];
    const float* ap = ea + (size_t)es * 6;
    float a0 = ap[0], a1 = ap[1], a2 = ap[2], a3 = ap[3], a4 = ap[4], a5 = ap[5];

    short8 Y[4];
    #pragma unroll
    for (int kst = 0; kst < 4; ++kst) {
      short8 y;
      #pragma unroll
      for (int jj = 0; jj < 8; ++jj) {
        int k = kst*32 + q4*8 + jj;
        float4 wa = *(const float4*)&s_k1t[k*8];
        float4 wb = *(const float4*)&s_k1t[k*8 + 4];
        float v = wb.z + a0*wa.x + a1*wa.y + a2*wa.z
                + a3*wa.w + a4*wb.x + a5*wb.y;
        v = fmaxf(v, 0.0f);
        y[jj] = (short)f2bf(v);
      }
      Y[kst] = y;
    }

    f32x4 acc[8];
    #pragma unroll
    for (int jt = 0; jt < 8; ++jt) acc[jt] = f32x4{0.f,0.f,0.f,0.f};
    #pragma unroll
    for (int kst = 0; kst < 4; ++kst) {
      #pragma unroll
      for (int jt = 0; jt < 8; ++jt) {
        short8 X = *(const short8*)&s_w2[(jt*4 + kst)*512 + lane*8];
        acc[jt] = __builtin_amdgcn_mfma_f32_16x16x32_bf16(X, Y[kst], acc[jt], 0, 0, 0);
      }
    }

    if (i < e1) {
      size_t hb = (size_t)((i0 - e0) >> 4) * 2048;
      #pragma unroll
      for (int jt = 0; jt < 8; ++jt) {
        int jb = jt*16 + q4*4;
        float v0 = fmaxf(acc[jt][0] + s_b2[jb+0], 0.0f);
        float v1 = fmaxf(acc[jt][1] + s_b2[jb+1], 0.0f);
        float v2 = fmaxf(acc[jt][2] + s_b2[jb+2], 0.0f);
        float v3 = fmaxf(acc[jt][3] + s_b2[jb+3], 0.0f);
        uint2 pk;
        pk.x = ((uint32_t)f2bf(v1) << 16) | f2bf(v0);
        pk.y = ((uint32_t)f2bf(v3) << 16) | f2bf(v2);
        size_t off = hb + (size_t)(((jt*2 + (q4>>1))*16 + m16)*8 + (q4&1)*4);
        *(uint2*)&h2[off] = pk;
      }
    }
  }
}

// ---------- fused v7 (r12/r15, unchanged): 512 threads = 8 waves ----------
__global__ __launch_bounds__(512) void k_fused(
    const uint16_t* __restrict__ h2, const uint16_t* __restrict__ w3t,
    const float* __restrict__ k3b, const float* __restrict__ feat,
    const int* __restrict__ srcS, float* __restrict__ msg, int e0, int e1) {
  __shared__ uint16_t s_w3[32768];   // 64KB = 4096 uint4; 8 iters x 512 = 4096 ✓
  __shared__ float s_b3[256];
  int tid = threadIdx.x;
  #pragma unroll
  for (int it = 0; it < 8; ++it) {
    int g = it * 512 + tid;
    int tile = g >> 6, o8 = g & 63;
    ((uint4*)s_w3)[tile * 64 + (o8 & 3) * 16 + (o8 >> 2)] = ((const uint4*)w3t)[g];
  }
  if (tid < 256) s_b3[tid] = k3b[tid];
  __syncthreads();

  int w = tid >> 6, lane = tid & 63;
  int m16 = lane & 15, q4 = lane >> 4;
  int wbase = e0 + blockIdx.x * 256 + w * 32;
  int maxt = (e1 - 1 - e0) >> 4;

  // Y fragments for both tiles (coalesced 1KB-per-kst global reads)
  short8 Y[2][4];
  #pragma unroll
  for (int et = 0; et < 2; ++et) {
    int t = ((wbase - e0) >> 4) + et; if (t > maxt) t = maxt;
    const uint16_t* hb = h2 + (size_t)t * 2048;
    #pragma unroll
    for (int kst = 0; kst < 4; ++kst)
      Y[et][kst] = *(const short8*)&hb[(size_t)((kst*4 + q4)*16 + m16)*8];
  }

  // feat gather for both edges
  float f[2][16];
  #pragma unroll
  for (int et = 0; et < 2; ++et) {
    int i = wbase + et*16 + m16;
    int ic = i < e1 ? i : e1 - 1;
    int s = srcS[ic];
    const float4* fp = (const float4*)(feat + (size_t)s * 16);
    #pragma unroll
    for (int q = 0; q < 4; ++q) {
      float4 t = fp[q];
      f[et][q*4] = t.x; f[et][q*4+1] = t.y; f[et][q*4+2] = t.z; f[et][q*4+3] = t.w;
    }
  }

  // MFMA sweep: one X read feeds both tiles; all 32 accumulators stay live.
  f32x4 acc[2][16];
  #pragma unroll
  for (int et = 0; et < 2; ++et)
    #pragma unroll
    for (int t = 0; t < 16; ++t) acc[et][t] = f32x4{0.f,0.f,0.f,0.f};
  #pragma unroll
  for (int kst = 0; kst < 4; ++kst) {
    #pragma unroll
    for (int oct = 0; oct < 16; ++oct) {
      short8 X = *(const short8*)&s_w3[(oct*4 + kst)*512 + lane*8];
      acc[0][oct] = __builtin_amdgcn_mfma_f32_16x16x32_bf16(X, Y[0][kst], acc[0][oct], 0, 0, 0);
      acc[1][oct] = __builtin_amdgcn_mfma_f32_16x16x32_bf16(X, Y[1][kst], acc[1][oct], 0, 0, 0);
    }
  }

  // fold + store (after all MFMAs — invariant)
  #pragma unroll
  for (int et = 0; et < 2; ++et) {
    float4 m = {0.f, 0.f, 0.f, 0.f};
    #pragma unroll
    for (int ii = 0; ii < 16; ++ii) {
      float4 bv = *(const float4*)&s_b3[ii*16 + q4*4];
      float fi = f[et][ii];
      m.x += fi * (acc[et][ii][0] + bv.x);
      m.y += fi * (acc[et][ii][1] + bv.y);
      m.z += fi * (acc[et][ii][2] + bv.z);
      m.w += fi * (acc[et][ii][3] + bv.w);
    }
    int i = wbase + et*16 + m16;
    if (i < e1) *(float4*)(msg + (size_t)i * 16 + q4 * 4) = m;
  }
}

// ---------- segment-sum + node update fused ----------
__global__ __launch_bounds__(256) void k_agg(
    const float* __restrict__ msg, const int* __restrict__ rowptr,
    const float* __restrict__ fin, const float* __restrict__ rootw,
    const float* __restrict__ convb, float* __restrict__ fout, int N) {
  __shared__ float s_rw[256];
  __shared__ float s_cb[16];
  int tid = threadIdx.x;
  s_rw[tid] = rootw[tid];
  if (tid < 16) s_cb[tid] = convb[tid];
  __syncthreads();
  int n = blockIdx.x * 16 + (tid >> 4);
  int ch = tid & 15;
  if (n >= N) return;
  int p0 = rowptr[n], p1 = rowptr[n+1];
  float sum = 0.0f;
  for (int p = p0; p < p1; ++p) sum += msg[(size_t)p * 16 + ch];
  float di = 1.0f / fmaxf((float)(p1 - p0), 1.0f);
  float o = s_cb[ch] + sum * di;
  const float* fp = fin + (size_t)n * 16;
  #pragma unroll
  for (int i = 0; i < 16; ++i) o += fp[i] * s_rw[i*16 + ch];
  fout[(size_t)n * 16 + ch] = fmaxf(o, 0.0f);
}

// ---------- head ----------
__global__ __launch_bounds__(256) void k_out(const float* __restrict__ feat,
                                             const float* __restrict__ w,
                                             const float* __restrict__ b,
                                             float* __restrict__ out, int N) {
  int n = blockIdx.x * 256 + threadIdx.x;
  if (n >= N) return;
  const float4* fp = (const float4*)(feat + (size_t)n*16);
  float acc = b[0];
  #pragma unroll
  for (int q = 0; q < 4; ++q) {
    float4 t = fp[q];
    acc += t.x*w[q*4] + t.y*w[q*4+1] + t.z*w[q*4+2] + t.w*w[q*4+3];
  }
  out[n] = acc;
}

extern "C" void kernel_launch(void* const* d_in, const int* in_sizes, int n_in,
                              void* d_out, int out_size, void* d_ws, size_t ws_size,
                              hipStream_t stream) {
  const float* x     = (const float*)d_in[0];
  const void*  ei    = d_in[1];
  const float* ea    = (const float*)d_in[2];
  const float* fc1w  = (const float*)d_in[3];
  const float* fc1b  = (const float*)d_in[4];
  const float* k1w   = (const float*)d_in[5];
  const float* k1b   = (const float*)d_in[6];
  const float* k2w   = (const float*)d_in[7];
  const float* k2b   = (const float*)d_in[8];
  const float* k3w   = (const float*)d_in[9];
  const float* k3b   = (const float*)d_in[10];
  const float* rootw = (const float*)d_in[11];
  const float* convb = (const float*)d_in[12];
  const float* fc2w  = (const float*)d_in[13];
  const float* fc2b  = (const float*)d_in[14];
  int N = in_sizes[0];
  int E = in_sizes[1] / 2;

  char* base = (char*)d_ws;
  size_t off = 0;
  auto alloc = [&](size_t bytes) -> void* {
    void* p = base + off;
    off = (off + bytes + 255) & ~(size_t)255;
    return p;
  };
  int*      idx    = (int*)alloc((size_t)2*E*sizeof(int));
  int*      flag   = (int*)alloc(256);
  int*      rowptr = (int*)alloc((size_t)(N+1)*sizeof(int));
  int*      rowcur = (int*)alloc((size_t)N*sizeof(int));
  int*      bsum   = (int*)alloc(1024*sizeof(int));
  int*      eid    = (int*)alloc((size_t)E*sizeof(int));
  int*      srcS   = (int*)alloc((size_t)E*sizeof(int));
  float*    fA     = (float*)alloc((size_t)N*16*sizeof(float));
  float*    fB     = (float*)alloc((size_t)N*16*sizeof(float));
  float*    msg    = (float*)alloc((size_t)E*16*sizeof(float));
  uint16_t* w2t    = (uint16_t*)alloc(16384*2);
  uint16_t* w3t    = (uint16_t*)alloc(32768*2);
  float*    w1t    = (float*)alloc(1024*sizeof(float));
  if (off > ws_size) return;

  long long avail = (long long)ws_size - (long long)off;
  long long fullBytes = (long long)E * 256;
  int chunkE;
  if (avail >= fullBytes) {
    chunkE = E;
  } else {
    chunkE = (int)((avail / 256) & ~511LL);
    if (chunkE < 512) chunkE = 512;
  }
  uint16_t* h2 = (uint16_t*)alloc((size_t)chunkE * 256);
  bool full = (chunkE >= E);

  int* srcI = idx;
  int* dstI = idx + E;

  int n64 = E < 1024 ? E : 1024;
  k_detect<<<1, 256, 0, stream>>>((const long long*)ei, n64, (long long)N, flag);
  k_convert<<<(2*E + 255)/256, 256, 0, stream>>>(ei, 2*E, flag, idx);

  int nbN = (N + 255) / 256;
  k_zeroi<<<nbN, 256, 0, stream>>>(rowcur, N);
  k_count<<<(E + 255)/256, 256, 0, stream>>>(dstI, E, rowcur);
  k_scan1<<<nbN, 256, 0, stream>>>(rowcur, N, rowptr, bsum);
  k_scan2<<<1, 64, 0, stream>>>(bsum, nbN);
  k_scan3<<<nbN, 256, 0, stream>>>(rowptr, bsum, N, E);
  k_copyi<<<nbN, 256, 0, stream>>>(rowptr, rowcur, N);
  k_scatter<<<(E + 255)/256, 256, 0, stream>>>(srcI, dstI, E, rowcur, eid, srcS);

  k_prep<<<128, 256, 0, stream>>>(k2w, k3w, k1w, k1b, w2t, w3t, w1t);
  k_feat0<<<(N + 255)/256, 256, 0, stream>>>(x, fc1w, fc1b, fA, N);
  if (full)
    k_mlp12<<<(E + 255)/256, 512, 0, stream>>>(ea, eid, w1t, w2t, k2b, h2, 0, E);

  float* fin = fA;
  float* fout = fB;
  int nbAgg = (N + 15) / 16;
  for (int d = 0; d < 4; ++d) {
    if (full) {
      k_fused<<<(E + 255)/256, 512, 0, stream>>>(h2, w3t, k3b, fin, srcS, msg, 0, E);
    } else {
      for (int i0 = 0; i0 < E; i0 += chunkE) {
        int i1 = i0 + chunkE < E ? i0 + chunkE : E;
        k_mlp12<<<(i1 - i0 + 255)/256, 512, 0, stream>>>(ea, eid, w1t, w2t, k2b, h2, i0, i1);
        k_fused<<<(i1 - i0 + 255)/256, 512, 0, stream>>>(h2, w3t, k3b, fin, srcS, msg, i0, i1);
      }
    }
    k_agg<<<nbAgg, 256, 0, stream>>>(msg, rowptr, fin, rootw, convb, fout, N);
    float* t = fin; fin = fout; fout = t;
  }
  k_out<<<(N + 255)/256, 256, 0, stream>>>(fin, fc2w, fc2b, (float*)d_out, N);
}

// Round 18
// 382.725 us; speedup vs baseline: 1.5796x; 1.0102x over previous
//
#include <hip/hip_runtime.h>
#include <stdint.h>

typedef __attribute__((ext_vector_type(8))) short short8;
typedef __attribute__((ext_vector_type(4))) float f32x4;

static __device__ __forceinline__ uint16_t f2bf(float f) {
  uint32_t u = __builtin_bit_cast(uint32_t, f);
  u += 0x7FFFu + ((u >> 16) & 1u);
  return (uint16_t)(u >> 16);
}

// ---------- utilities ----------
__global__ __launch_bounds__(256) void k_zeroi(int* __restrict__ p, int n) {
  int i = blockIdx.x * 256 + threadIdx.x;
  if (i < n) p[i] = 0;
}
__global__ __launch_bounds__(256) void k_copyi(const int* __restrict__ a,
                                               int* __restrict__ b, int n) {
  int i = blockIdx.x * 256 + threadIdx.x;
  if (i < n) b[i] = a[i];
}

// ---------- index dtype detection + conversion ----------
__global__ __launch_bounds__(256) void k_detect(const long long* ei64, int n64,
                                                long long nmax, int* flag) {
  __shared__ int ok;
  if (threadIdx.x == 0) ok = 1;
  __syncthreads();
  for (int i = threadIdx.x; i < n64; i += 256) {
    long long v = ei64[i];
    if (v < 0 || v >= nmax) atomicAnd(&ok, 0);
  }
  __syncthreads();
  if (threadIdx.x == 0) *flag = ok;
}

__global__ __launch_bounds__(256) void k_convert(const void* ei, int e2,
                                                 const int* __restrict__ flag,
                                                 int* __restrict__ out) {
  int i = blockIdx.x * 256 + threadIdx.x;
  if (i >= e2) return;
  out[i] = (*flag) ? (int)((const long long*)ei)[i] : ((const int*)ei)[i];
}

// ---------- counting sort by dst ----------
__global__ __launch_bounds__(256) void k_count(const int* __restrict__ dst, int E,
                                               int* __restrict__ cnt) {
  int i = blockIdx.x * 256 + threadIdx.x;
  if (i < E) atomicAdd(&cnt[dst[i]], 1);
}

__global__ __launch_bounds__(256) void k_scan1(const int* __restrict__ cnt, int n,
                                               int* __restrict__ excl,
                                               int* __restrict__ bsum) {
  __shared__ int s[256];
  int i = blockIdx.x * 256 + threadIdx.x;
  int v = (i < n) ? cnt[i] : 0;
  s[threadIdx.x] = v;
  __syncthreads();
  #pragma unroll
  for (int off = 1; off < 256; off <<= 1) {
    int t = (threadIdx.x >= off) ? s[threadIdx.x - off] : 0;
    __syncthreads();
    s[threadIdx.x] += t;
    __syncthreads();
  }
  if (i < n) excl[i] = s[threadIdx.x] - v;
  if (threadIdx.x == 255) bsum[blockIdx.x] = s[255];
}
__global__ void k_scan2(int* bsum, int nb) {
  if (threadIdx.x == 0 && blockIdx.x == 0) {
    int run = 0;
    for (int b = 0; b < nb; ++b) { int t = bsum[b]; bsum[b] = run; run += t; }
  }
}
__global__ __launch_bounds__(256) void k_scan3(int* __restrict__ excl,
                                               const int* __restrict__ bsum,
                                               int n, int E) {
  int i = blockIdx.x * 256 + threadIdx.x;
  if (i < n) excl[i] += bsum[blockIdx.x];
  if (i == 0) excl[n] = E;
}

__global__ __launch_bounds__(256) void k_scatter(const int* __restrict__ src,
                                                 const int* __restrict__ dst, int E,
                                                 int* __restrict__ rowcur,
                                                 int* __restrict__ eid,
                                                 int* __restrict__ srcS) {
  int e = blockIdx.x * 256 + threadIdx.x;
  if (e >= E) return;
  int d = dst[e];
  int pos = atomicAdd(&rowcur[d], 1);
  eid[pos] = e;
  srcS[pos] = src[e];
}

// ---------- weight pre-tiling into MFMA fragment order (r4/r15 layout) ----------
__global__ __launch_bounds__(256) void k_prep(const float* __restrict__ k2w,
                                              const float* __restrict__ k3w,
                                              uint16_t* __restrict__ w2t,
                                              uint16_t* __restrict__ w3t) {
  int d = blockIdx.x * 256 + threadIdx.x;
  int tile = d >> 9, ww = d & 511;
  int m16 = ww >> 5, q4 = (ww >> 3) & 3, jj = ww & 7;
  int ot = tile >> 2, kst = tile & 3;
  int k = kst * 32 + q4 * 8 + jj;
  if (d < 16384) {
    int j = ot * 16 + m16;
    w2t[d] = f2bf(k2w[k * 128 + j]);
  }
  if (d < 32768) {
    int oc = ot * 16 + m16;
    w3t[d] = f2bf(k3w[k * 256 + oc]);
  }
}

// ---------- feat0 = x @ fc1_w + fc1_b ----------
__global__ __launch_bounds__(256) void k_feat0(const float* __restrict__ x,
                                               const float* __restrict__ w,
                                               const float* __restrict__ b,
                                               float* __restrict__ feat, int N) {
  int n = blockIdx.x * 256 + threadIdx.x;
  if (n >= N) return;
  float xv = x[n];
  float4* fp = (float4*)(feat + (size_t)n * 16);
  #pragma unroll
  for (int q = 0; q < 4; ++q) {
    float4 v;
    v.x = xv * w[q*4+0] + b[q*4+0];
    v.y = xv * w[q*4+1] + b[q*4+1];
    v.z = xv * w[q*4+2] + b[q*4+2];
    v.w = xv * w[q*4+3] + b[q*4+3];
    fp[q] = v;
  }
}

// ---------- edge MLP layers 1+2 (EXACT r15): 512 threads, ET=2, scalar s_k1 reads ----------
// r15 measured: 52us, VGPR 64, occ 28%, conflicts 1.2M (staging only). r13/r16 spilled
// by hoisting state; r17's padded-b128 weight table caused 4-way bank conflicts
// (32B stride -> q4 groups 256B apart -> same banks). Scalar stride-128 reads hit
// banks {0,8,16,24} across q4 groups: conflict-free. CLOSED — do not re-tune.
__global__ __launch_bounds__(512) void k_mlp12(
    const float* __restrict__ ea, const int* __restrict__ eid,
    const float* __restrict__ k1w, const float* __restrict__ k1b,
    const uint16_t* __restrict__ w2t, const float* __restrict__ k2b,
    uint16_t* __restrict__ h2, int e0, int e1) {
  __shared__ uint16_t s_w2[16384];   // 32KB, lane-linear in-tile order
  __shared__ float s_k1[768];
  __shared__ float s_b1[128];
  __shared__ float s_b2[128];
  int tid = threadIdx.x;
  #pragma unroll
  for (int it = 0; it < 4; ++it) {   // 4 x 512 = 2048 uint4 = full 32KB tile
    int g = it * 512 + tid;
    int tile = g >> 6, o8 = g & 63;
    ((uint4*)s_w2)[tile * 64 + (o8 & 3) * 16 + (o8 >> 2)] = ((const uint4*)w2t)[g];
  }
  for (int i = tid; i < 768; i += 512) s_k1[i] = k1w[i];
  if (tid < 128) { s_b1[tid] = k1b[tid]; s_b2[tid] = k2b[tid]; }
  __syncthreads();

  int w = tid >> 6, lane = tid & 63;
  int m16 = lane & 15, q4 = lane >> 4;
  int wbase = e0 + blockIdx.x * 256 + w * 32;

  #pragma unroll
  for (int et = 0; et < 2; ++et) {
    int i0 = wbase + et * 16;
    int i = i0 + m16;
    int ic = i < e1 ? i : e1 - 1;
    int es = eid[ic];
    const float* ap = ea + (size_t)es * 6;
    float a0 = ap[0], a1 = ap[1], a2 = ap[2], a3 = ap[3], a4 = ap[4], a5 = ap[5];

    short8 Y[4];
    #pragma unroll
    for (int kst = 0; kst < 4; ++kst) {
      short8 y;
      #pragma unroll
      for (int jj = 0; jj < 8; ++jj) {
        int k = kst*32 + q4*8 + jj;
        float v = s_b1[k] + a0*s_k1[k] + a1*s_k1[128+k] + a2*s_k1[256+k]
                + a3*s_k1[384+k] + a4*s_k1[512+k] + a5*s_k1[640+k];
        v = fmaxf(v, 0.0f);
        y[jj] = (short)f2bf(v);
      }
      Y[kst] = y;
    }

    f32x4 acc[8];
    #pragma unroll
    for (int jt = 0; jt < 8; ++jt) acc[jt] = f32x4{0.f,0.f,0.f,0.f};
    #pragma unroll
    for (int kst = 0; kst < 4; ++kst) {
      #pragma unroll
      for (int jt = 0; jt < 8; ++jt) {
        short8 X = *(const short8*)&s_w2[(jt*4 + kst)*512 + lane*8];
        acc[jt] = __builtin_amdgcn_mfma_f32_16x16x32_bf16(X, Y[kst], acc[jt], 0, 0, 0);
      }
    }

    if (i < e1) {
      size_t hb = (size_t)((i0 - e0) >> 4) * 2048;
      #pragma unroll
      for (int jt = 0; jt < 8; ++jt) {
        int jb = jt*16 + q4*4;
        float v0 = fmaxf(acc[jt][0] + s_b2[jb+0], 0.0f);
        float v1 = fmaxf(acc[jt][1] + s_b2[jb+1], 0.0f);
        float v2 = fmaxf(acc[jt][2] + s_b2[jb+2], 0.0f);
        float v3 = fmaxf(acc[jt][3] + s_b2[jb+3], 0.0f);
        uint2 pk;
        pk.x = ((uint32_t)f2bf(v1) << 16) | f2bf(v0);
        pk.y = ((uint32_t)f2bf(v3) << 16) | f2bf(v2);
        size_t off = hb + (size_t)(((jt*2 + (q4>>1))*16 + m16)*8 + (q4&1)*4);
        *(uint2*)&h2[off] = pk;
      }
    }
  }
}

// ---------- fused v8: 1024 threads = 16 waves, ET=1 (r12 recipe applied again) ----------
// Block = 256 edges (same grid/staging totals as r12). Wave covers ONE 16-edge tile:
// acc[16]+Y[4]+f[16] ~= 115 VGPR, safely under the launch_bounds(1024) 128-cap
// (no spill; r16's spill was ~200 live under the cap). Safe-pattern sweep:
// kst-outer/oct-inner, acc arrays, fold AFTER the full sweep — invariant.
__global__ __launch_bounds__(1024) void k_fused(
    const uint16_t* __restrict__ h2, const uint16_t* __restrict__ w3t,
    const float* __restrict__ k3b, const float* __restrict__ feat,
    const int* __restrict__ srcS, float* __restrict__ msg, int e0, int e1) {
  __shared__ uint16_t s_w3[32768];   // 64KB = 4096 uint4; 4 iters x 1024 = 4096 ✓
  __shared__ float s_b3[256];
  int tid = threadIdx.x;
  #pragma unroll
  for (int it = 0; it < 4; ++it) {
    int g = it * 1024 + tid;
    int tile = g >> 6, o8 = g & 63;
    ((uint4*)s_w3)[tile * 64 + (o8 & 3) * 16 + (o8 >> 2)] = ((const uint4*)w3t)[g];
  }
  if (tid < 256) s_b3[tid] = k3b[tid];
  __syncthreads();

  int w = tid >> 6, lane = tid & 63;
  int m16 = lane & 15, q4 = lane >> 4;
  int wbase = e0 + blockIdx.x * 256 + w * 16;
  int maxt = (e1 - 1 - e0) >> 4;

  // Y fragments for this wave's tile (coalesced 1KB-per-kst global reads)
  short8 Y[4];
  {
    int t = (wbase - e0) >> 4; if (t > maxt) t = maxt;
    const uint16_t* hb = h2 + (size_t)t * 2048;
    #pragma unroll
    for (int kst = 0; kst < 4; ++kst)
      Y[kst] = *(const short8*)&hb[(size_t)((kst*4 + q4)*16 + m16)*8];
  }

  // feat gather for this lane's edge
  int i = wbase + m16;
  int ic = i < e1 ? i : e1 - 1;
  int s = srcS[ic];
  float f[16];
  {
    const float4* fp = (const float4*)(feat + (size_t)s * 16);
    #pragma unroll
    for (int q = 0; q < 4; ++q) {
      float4 t = fp[q];
      f[q*4] = t.x; f[q*4+1] = t.y; f[q*4+2] = t.z; f[q*4+3] = t.w;
    }
  }

  // MFMA sweep (kst-outer/oct-inner, acc array, fold after — invariant)
  f32x4 acc[16];
  #pragma unroll
  for (int t = 0; t < 16; ++t) acc[t] = f32x4{0.f,0.f,0.f,0.f};
  #pragma unroll
  for (int kst = 0; kst < 4; ++kst) {
    #pragma unroll
    for (int oct = 0; oct < 16; ++oct) {
      short8 X = *(const short8*)&s_w3[(oct*4 + kst)*512 + lane*8];
      acc[oct] = __builtin_amdgcn_mfma_f32_16x16x32_bf16(X, Y[kst], acc[oct], 0, 0, 0);
    }
  }

  // fold + store
  float4 m = {0.f, 0.f, 0.f, 0.f};
  #pragma unroll
  for (int ii = 0; ii < 16; ++ii) {
    float4 bv = *(const float4*)&s_b3[ii*16 + q4*4];
    float fi = f[ii];
    m.x += fi * (acc[ii][0] + bv.x);
    m.y += fi * (acc[ii][1] + bv.y);
    m.z += fi * (acc[ii][2] + bv.z);
    m.w += fi * (acc[ii][3] + bv.w);
  }
  if (i < e1) *(float4*)(msg + (size_t)i * 16 + q4 * 4) = m;
}

// ---------- segment-sum + node update fused ----------
__global__ __launch_bounds__(256) void k_agg(
    const float* __restrict__ msg, const int* __restrict__ rowptr,
    const float* __restrict__ fin, const float* __restrict__ rootw,
    const float* __restrict__ convb, float* __restrict__ fout, int N) {
  __shared__ float s_rw[256];
  __shared__ float s_cb[16];
  int tid = threadIdx.x;
  s_rw[tid] = rootw[tid];
  if (tid < 16) s_cb[tid] = convb[tid];
  __syncthreads();
  int n = blockIdx.x * 16 + (tid >> 4);
  int ch = tid & 15;
  if (n >= N) return;
  int p0 = rowptr[n], p1 = rowptr[n+1];
  float sum = 0.0f;
  for (int p = p0; p < p1; ++p) sum += msg[(size_t)p * 16 + ch];
  float di = 1.0f / fmaxf((float)(p1 - p0), 1.0f);
  float o = s_cb[ch] + sum * di;
  const float* fp = fin + (size_t)n * 16;
  #pragma unroll
  for (int i = 0; i < 16; ++i) o += fp[i] * s_rw[i*16 + ch];
  fout[(size_t)n * 16 + ch] = fmaxf(o, 0.0f);
}

// ---------- head ----------
__global__ __launch_bounds__(256) void k_out(const float* __restrict__ feat,
                                             const float* __restrict__ w,
                                             const float* __restrict__ b,
                                             float* __restrict__ out, int N) {
  int n = blockIdx.x * 256 + threadIdx.x;
  if (n >= N) return;
  const float4* fp = (const float4*)(feat + (size_t)n*16);
  float acc = b[0];
  #pragma unroll
  for (int q = 0; q < 4; ++q) {
    float4 t = fp[q];
    acc += t.x*w[q*4] + t.y*w[q*4+1] + t.z*w[q*4+2] + t.w*w[q*4+3];
  }
  out[n] = acc;
}

extern "C" void kernel_launch(void* const* d_in, const int* in_sizes, int n_in,
                              void* d_out, int out_size, void* d_ws, size_t ws_size,
                              hipStream_t stream) {
  const float* x     = (const float*)d_in[0];
  const void*  ei    = d_in[1];
  const float* ea    = (const float*)d_in[2];
  const float* fc1w  = (const float*)d_in[3];
  const float* fc1b  = (const float*)d_in[4];
  const float* k1w   = (const float*)d_in[5];
  const float* k1b   = (const float*)d_in[6];
  const float* k2w   = (const float*)d_in[7];
  const float* k2b   = (const float*)d_in[8];
  const float* k3w   = (const float*)d_in[9];
  const float* k3b   = (const float*)d_in[10];
  const float* rootw = (const float*)d_in[11];
  const float* convb = (const float*)d_in[12];
  const float* fc2w  = (const float*)d_in[13];
  const float* fc2b  = (const float*)d_in[14];
  int N = in_sizes[0];
  int E = in_sizes[1] / 2;

  char* base = (char*)d_ws;
  size_t off = 0;
  auto alloc = [&](size_t bytes) -> void* {
    void* p = base + off;
    off = (off + bytes + 255) & ~(size_t)255;
    return p;
  };
  int*      idx    = (int*)alloc((size_t)2*E*sizeof(int));
  int*      flag   = (int*)alloc(256);
  int*      rowptr = (int*)alloc((size_t)(N+1)*sizeof(int));
  int*      rowcur = (int*)alloc((size_t)N*sizeof(int));
  int*      bsum   = (int*)alloc(1024*sizeof(int));
  int*      eid    = (int*)alloc((size_t)E*sizeof(int));
  int*      srcS   = (int*)alloc((size_t)E*sizeof(int));
  float*    fA     = (float*)alloc((size_t)N*16*sizeof(float));
  float*    fB     = (float*)alloc((size_t)N*16*sizeof(float));
  float*    msg    = (float*)alloc((size_t)E*16*sizeof(float));
  uint16_t* w2t    = (uint16_t*)alloc(16384*2);
  uint16_t* w3t    = (uint16_t*)alloc(32768*2);
  if (off > ws_size) return;

  long long avail = (long long)ws_size - (long long)off;
  long long fullBytes = (long long)E * 256;
  int chunkE;
  if (avail >= fullBytes) {
    chunkE = E;
  } else {
    chunkE = (int)((avail / 256) & ~511LL);
    if (chunkE < 512) chunkE = 512;
  }
  uint16_t* h2 = (uint16_t*)alloc((size_t)chunkE * 256);
  bool full = (chunkE >= E);

  int* srcI = idx;
  int* dstI = idx + E;

  int n64 = E < 1024 ? E : 1024;
  k_detect<<<1, 256, 0, stream>>>((const long long*)ei, n64, (long long)N, flag);
  k_convert<<<(2*E + 255)/256, 256, 0, stream>>>(ei, 2*E, flag, idx);

  int nbN = (N + 255) / 256;
  k_zeroi<<<nbN, 256, 0, stream>>>(rowcur, N);
  k_count<<<(E + 255)/256, 256, 0, stream>>>(dstI, E, rowcur);
  k_scan1<<<nbN, 256, 0, stream>>>(rowcur, N, rowptr, bsum);
  k_scan2<<<1, 64, 0, stream>>>(bsum, nbN);
  k_scan3<<<nbN, 256, 0, stream>>>(rowptr, bsum, N, E);
  k_copyi<<<nbN, 256, 0, stream>>>(rowptr, rowcur, N);
  k_scatter<<<(E + 255)/256, 256, 0, stream>>>(srcI, dstI, E, rowcur, eid, srcS);

  k_prep<<<128, 256, 0, stream>>>(k2w, k3w, w2t, w3t);
  k_feat0<<<(N + 255)/256, 256, 0, stream>>>(x, fc1w, fc1b, fA, N);
  if (full)
    k_mlp12<<<(E + 255)/256, 512, 0, stream>>>(ea, eid, k1w, k1b, w2t, k2b, h2, 0, E);

  float* fin = fA;
  float* fout = fB;
  int nbAgg = (N + 15) / 16;
  for (int d = 0; d < 4; ++d) {
    if (full) {
      k_fused<<<(E + 255)/256, 1024, 0, stream>>>(h2, w3t, k3b, fin, srcS, msg, 0, E);
    } else {
      for (int i0 = 0; i0 < E; i0 += chunkE) {
        int i1 = i0 + chunkE < E ? i0 + chunkE : E;
        k_mlp12<<<(i1 - i0 + 255)/256, 512, 0, stream>>>(ea, eid, k1w, k1b, w2t, k2b, h2, i0, i1);
        k_fused<<<(i1 - i0 + 255)/256, 1024, 0, stream>>>(h2, w3t, k3b, fin, srcS, msg, i0, i1);
      }
    }
    k_agg<<<nbAgg, 256, 0, stream>>>(msg, rowptr, fin, rootw, convb, fout, N);
    float* t = fin; fin = fout; fout = t;
  }
  k_out<<<(N + 255)/256, 256, 0, stream>>>(fin, fc2w, fc2b, (float*)d_out, N);
}

// Round 19
// 372.368 us; speedup vs baseline: 1.6236x; 1.0278x over previous
//
#include <hip/hip_runtime.h>
#include <stdint.h>

typedef __attribute__((ext_vector_type(8))) short short8;
typedef __attribute__((ext_vector_type(4))) float f32x4;

static __device__ __forceinline__ uint16_t f2bf(float f) {
  uint32_t u = __builtin_bit_cast(uint32_t, f);
  u += 0x7FFFu + ((u >> 16) & 1u);
  return (uint16_t)(u >> 16);
}

// ---------- utilities ----------
__global__ __launch_bounds__(256) void k_zeroi(int* __restrict__ p, int n) {
  int i = blockIdx.x * 256 + threadIdx.x;
  if (i < n) p[i] = 0;
}
__global__ __launch_bounds__(256) void k_copyi(const int* __restrict__ a,
                                               int* __restrict__ b, int n) {
  int i = blockIdx.x * 256 + threadIdx.x;
  if (i < n) b[i] = a[i];
}

// ---------- index dtype detection + conversion ----------
__global__ __launch_bounds__(256) void k_detect(const long long* ei64, int n64,
                                                long long nmax, int* flag) {
  __shared__ int ok;
  if (threadIdx.x == 0) ok = 1;
  __syncthreads();
  for (int i = threadIdx.x; i < n64; i += 256) {
    long long v = ei64[i];
    if (v < 0 || v >= nmax) atomicAnd(&ok, 0);
  }
  __syncthreads();
  if (threadIdx.x == 0) *flag = ok;
}

__global__ __launch_bounds__(256) void k_convert(const void* ei, int e2,
                                                 const int* __restrict__ flag,
                                                 int* __restrict__ out) {
  int i = blockIdx.x * 256 + threadIdx.x;
  if (i >= e2) return;
  out[i] = (*flag) ? (int)((const long long*)ei)[i] : ((const int*)ei)[i];
}

// ---------- counting sort by dst ----------
__global__ __launch_bounds__(256) void k_count(const int* __restrict__ dst, int E,
                                               int* __restrict__ cnt) {
  int i = blockIdx.x * 256 + threadIdx.x;
  if (i < E) atomicAdd(&cnt[dst[i]], 1);
}

__global__ __launch_bounds__(256) void k_scan1(const int* __restrict__ cnt, int n,
                                               int* __restrict__ excl,
                                               int* __restrict__ bsum) {
  __shared__ int s[256];
  int i = blockIdx.x * 256 + threadIdx.x;
  int v = (i < n) ? cnt[i] : 0;
  s[threadIdx.x] = v;
  __syncthreads();
  #pragma unroll
  for (int off = 1; off < 256; off <<= 1) {
    int t = (threadIdx.x >= off) ? s[threadIdx.x - off] : 0;
    __syncthreads();
    s[threadIdx.x] += t;
    __syncthreads();
  }
  if (i < n) excl[i] = s[threadIdx.x] - v;
  if (threadIdx.x == 255) bsum[blockIdx.x] = s[255];
}
__global__ void k_scan2(int* bsum, int nb) {
  if (threadIdx.x == 0 && blockIdx.x == 0) {
    int run = 0;
    for (int b = 0; b < nb; ++b) { int t = bsum[b]; bsum[b] = run; run += t; }
  }
}
__global__ __launch_bounds__(256) void k_scan3(int* __restrict__ excl,
                                               const int* __restrict__ bsum,
                                               int n, int E) {
  int i = blockIdx.x * 256 + threadIdx.x;
  if (i < n) excl[i] += bsum[blockIdx.x];
  if (i == 0) excl[n] = E;
}

__global__ __launch_bounds__(256) void k_scatter(const int* __restrict__ src,
                                                 const int* __restrict__ dst, int E,
                                                 int* __restrict__ rowcur,
                                                 int* __restrict__ eid,
                                                 int* __restrict__ srcS) {
  int e = blockIdx.x * 256 + threadIdx.x;
  if (e >= E) return;
  int d = dst[e];
  int pos = atomicAdd(&rowcur[d], 1);
  eid[pos] = e;
  srcS[pos] = src[e];
}

// ---------- weight pre-tiling into MFMA fragment order ----------
__global__ __launch_bounds__(256) void k_prep(const float* __restrict__ k2w,
                                              const float* __restrict__ k3w,
                                              uint16_t* __restrict__ w2t,
                                              uint16_t* __restrict__ w3t) {
  int d = blockIdx.x * 256 + threadIdx.x;
  int tile = d >> 9, ww = d & 511;
  int m16 = ww >> 5, q4 = (ww >> 3) & 3, jj = ww & 7;
  int ot = tile >> 2, kst = tile & 3;
  int k = kst * 32 + q4 * 8 + jj;
  if (d < 16384) {
    int j = ot * 16 + m16;
    w2t[d] = f2bf(k2w[k * 128 + j]);
  }
  if (d < 32768) {
    int oc = ot * 16 + m16;
    w3t[d] = f2bf(k3w[k * 256 + oc]);
  }
}

// ---------- feat0 = x @ fc1_w + fc1_b ----------
__global__ __launch_bounds__(256) void k_feat0(const float* __restrict__ x,
                                               const float* __restrict__ w,
                                               const float* __restrict__ b,
                                               float* __restrict__ feat, int N) {
  int n = blockIdx.x * 256 + threadIdx.x;
  if (n >= N) return;
  float xv = x[n];
  float4* fp = (float4*)(feat + (size_t)n * 16);
  #pragma unroll
  for (int q = 0; q < 4; ++q) {
    float4 v;
    v.x = xv * w[q*4+0] + b[q*4+0];
    v.y = xv * w[q*4+1] + b[q*4+1];
    v.z = xv * w[q*4+2] + b[q*4+2];
    v.w = xv * w[q*4+3] + b[q*4+3];
    fp[q] = v;
  }
}

// ---------- edge MLP layers 1+2 (r15, CLOSED): 512 threads, ET=2 ----------
// 52us, VGPR 64, occ 28%. Scalar stride-128 s_k1 reads are conflict-free
// (banks {0,8,16,24} across q4 groups); padded-b128 table (r17) conflicted 4-way;
// state-hoisting (r13/r16) spilled. Do not re-tune.
__global__ __launch_bounds__(512) void k_mlp12(
    const float* __restrict__ ea, const int* __restrict__ eid,
    const float* __restrict__ k1w, const float* __restrict__ k1b,
    const uint16_t* __restrict__ w2t, const float* __restrict__ k2b,
    uint16_t* __restrict__ h2, int e0, int e1) {
  __shared__ uint16_t s_w2[16384];   // 32KB, lane-linear in-tile order
  __shared__ float s_k1[768];
  __shared__ float s_b1[128];
  __shared__ float s_b2[128];
  int tid = threadIdx.x;
  #pragma unroll
  for (int it = 0; it < 4; ++it) {   // 4 x 512 = 2048 uint4 = full 32KB tile
    int g = it * 512 + tid;
    int tile = g >> 6, o8 = g & 63;
    ((uint4*)s_w2)[tile * 64 + (o8 & 3) * 16 + (o8 >> 2)] = ((const uint4*)w2t)[g];
  }
  for (int i = tid; i < 768; i += 512) s_k1[i] = k1w[i];
  if (tid < 128) { s_b1[tid] = k1b[tid]; s_b2[tid] = k2b[tid]; }
  __syncthreads();

  int w = tid >> 6, lane = tid & 63;
  int m16 = lane & 15, q4 = lane >> 4;
  int wbase = e0 + blockIdx.x * 256 + w * 32;

  #pragma unroll
  for (int et = 0; et < 2; ++et) {
    int i0 = wbase + et * 16;
    int i = i0 + m16;
    int ic = i < e1 ? i : e1 - 1;
    int es = eid[ic];
    const float* ap = ea + (size_t)es * 6;
    float a0 = ap[0], a1 = ap[1], a2 = ap[2], a3 = ap[3], a4 = ap[4], a5 = ap[5];

    short8 Y[4];
    #pragma unroll
    for (int kst = 0; kst < 4; ++kst) {
      short8 y;
      #pragma unroll
      for (int jj = 0; jj < 8; ++jj) {
        int k = kst*32 + q4*8 + jj;
        float v = s_b1[k] + a0*s_k1[k] + a1*s_k1[128+k] + a2*s_k1[256+k]
                + a3*s_k1[384+k] + a4*s_k1[512+k] + a5*s_k1[640+k];
        v = fmaxf(v, 0.0f);
        y[jj] = (short)f2bf(v);
      }
      Y[kst] = y;
    }

    f32x4 acc[8];
    #pragma unroll
    for (int jt = 0; jt < 8; ++jt) acc[jt] = f32x4{0.f,0.f,0.f,0.f};
    #pragma unroll
    for (int kst = 0; kst < 4; ++kst) {
      #pragma unroll
      for (int jt = 0; jt < 8; ++jt) {
        short8 X = *(const short8*)&s_w2[(jt*4 + kst)*512 + lane*8];
        acc[jt] = __builtin_amdgcn_mfma_f32_16x16x32_bf16(X, Y[kst], acc[jt], 0, 0, 0);
      }
    }

    if (i < e1) {
      size_t hb = (size_t)((i0 - e0) >> 4) * 2048;
      #pragma unroll
      for (int jt = 0; jt < 8; ++jt) {
        int jb = jt*16 + q4*4;
        float v0 = fmaxf(acc[jt][0] + s_b2[jb+0], 0.0f);
        float v1 = fmaxf(acc[jt][1] + s_b2[jb+1], 0.0f);
        float v2 = fmaxf(acc[jt][2] + s_b2[jb+2], 0.0f);
        float v3 = fmaxf(acc[jt][3] + s_b2[jb+3], 0.0f);
        uint2 pk;
        pk.x = ((uint32_t)f2bf(v1) << 16) | f2bf(v0);
        pk.y = ((uint32_t)f2bf(v3) << 16) | f2bf(v2);
        size_t off = hb + (size_t)(((jt*2 + (q4>>1))*16 + m16)*8 + (q4&1)*4);
        *(uint2*)&h2[off] = pk;
      }
    }
  }
}

// ---------- fused (r12, CLOSED): 512 threads = 8 waves, 2 blocks/CU = 16 waves ----------
// ~48us. VGPR tier <=128 caps at 16 waves/CU; next tier needs <=64 (impossible with
// acc[2][16]+Y+f live). ET=1/1024thr (r18) and ILP-halving (r11) were neutral.
// Safe-pattern invariant: kst-outer/oct-inner, acc arrays, fold AFTER full sweep.
__global__ __launch_bounds__(512) void k_fused(
    const uint16_t* __restrict__ h2, const uint16_t* __restrict__ w3t,
    const float* __restrict__ k3b, const float* __restrict__ feat,
    const int* __restrict__ srcS, float* __restrict__ msg, int e0, int e1) {
  __shared__ uint16_t s_w3[32768];   // 64KB = 4096 uint4; 8 iters x 512 = 4096
  __shared__ float s_b3[256];
  int tid = threadIdx.x;
  #pragma unroll
  for (int it = 0; it < 8; ++it) {
    int g = it * 512 + tid;
    int tile = g >> 6, o8 = g & 63;
    ((uint4*)s_w3)[tile * 64 + (o8 & 3) * 16 + (o8 >> 2)] = ((const uint4*)w3t)[g];
  }
  if (tid < 256) s_b3[tid] = k3b[tid];
  __syncthreads();

  int w = tid >> 6, lane = tid & 63;
  int m16 = lane & 15, q4 = lane >> 4;
  int wbase = e0 + blockIdx.x * 256 + w * 32;
  int maxt = (e1 - 1 - e0) >> 4;

  // Y fragments for both tiles (coalesced 1KB-per-kst global reads)
  short8 Y[2][4];
  #pragma unroll
  for (int et = 0; et < 2; ++et) {
    int t = ((wbase - e0) >> 4) + et; if (t > maxt) t = maxt;
    const uint16_t* hb = h2 + (size_t)t * 2048;
    #pragma unroll
    for (int kst = 0; kst < 4; ++kst)
      Y[et][kst] = *(const short8*)&hb[(size_t)((kst*4 + q4)*16 + m16)*8];
  }

  // feat gather for both edges
  float f[2][16];
  #pragma unroll
  for (int et = 0; et < 2; ++et) {
    int i = wbase + et*16 + m16;
    int ic = i < e1 ? i : e1 - 1;
    int s = srcS[ic];
    const float4* fp = (const float4*)(feat + (size_t)s * 16);
    #pragma unroll
    for (int q = 0; q < 4; ++q) {
      float4 t = fp[q];
      f[et][q*4] = t.x; f[et][q*4+1] = t.y; f[et][q*4+2] = t.z; f[et][q*4+3] = t.w;
    }
  }

  // MFMA sweep: one X read feeds both tiles; all 32 accumulators stay live.
  f32x4 acc[2][16];
  #pragma unroll
  for (int et = 0; et < 2; ++et)
    #pragma unroll
    for (int t = 0; t < 16; ++t) acc[et][t] = f32x4{0.f,0.f,0.f,0.f};
  #pragma unroll
  for (int kst = 0; kst < 4; ++kst) {
    #pragma unroll
    for (int oct = 0; oct < 16; ++oct) {
      short8 X = *(const short8*)&s_w3[(oct*4 + kst)*512 + lane*8];
      acc[0][oct] = __builtin_amdgcn_mfma_f32_16x16x32_bf16(X, Y[0][kst], acc[0][oct], 0, 0, 0);
      acc[1][oct] = __builtin_amdgcn_mfma_f32_16x16x32_bf16(X, Y[1][kst], acc[1][oct], 0, 0, 0);
    }
  }

  // fold + store (after all MFMAs — invariant)
  #pragma unroll
  for (int et = 0; et < 2; ++et) {
    float4 m = {0.f, 0.f, 0.f, 0.f};
    #pragma unroll
    for (int ii = 0; ii < 16; ++ii) {
      float4 bv = *(const float4*)&s_b3[ii*16 + q4*4];
      float fi = f[et][ii];
      m.x += fi * (acc[et][ii][0] + bv.x);
      m.y += fi * (acc[et][ii][1] + bv.y);
      m.z += fi * (acc[et][ii][2] + bv.z);
      m.w += fi * (acc[et][ii][3] + bv.w);
    }
    int i = wbase + et*16 + m16;
    if (i < e1) *(float4*)(msg + (size_t)i * 16 + q4 * 4) = m;
  }
}

// ---------- segment-sum + node update fused ----------
__global__ __launch_bounds__(256) void k_agg(
    const float* __restrict__ msg, const int* __restrict__ rowptr,
    const float* __restrict__ fin, const float* __restrict__ rootw,
    const float* __restrict__ convb, float* __restrict__ fout, int N) {
  __shared__ float s_rw[256];
  __shared__ float s_cb[16];
  int tid = threadIdx.x;
  s_rw[tid] = rootw[tid];
  if (tid < 16) s_cb[tid] = convb[tid];
  __syncthreads();
  int n = blockIdx.x * 16 + (tid >> 4);
  int ch = tid & 15;
  if (n >= N) return;
  int p0 = rowptr[n], p1 = rowptr[n+1];
  float sum = 0.0f;
  for (int p = p0; p < p1; ++p) sum += msg[(size_t)p * 16 + ch];
  float di = 1.0f / fmaxf((float)(p1 - p0), 1.0f);
  float o = s_cb[ch] + sum * di;
  const float* fp = fin + (size_t)n * 16;
  #pragma unroll
  for (int i = 0; i < 16; ++i) o += fp[i] * s_rw[i*16 + ch];
  fout[(size_t)n * 16 + ch] = fmaxf(o, 0.0f);
}

// ---------- head ----------
__global__ __launch_bounds__(256) void k_out(const float* __restrict__ feat,
                                             const float* __restrict__ w,
                                             const float* __restrict__ b,
                                             float* __restrict__ out, int N) {
  int n = blockIdx.x * 256 + threadIdx.x;
  if (n >= N) return;
  const float4* fp = (const float4*)(feat + (size_t)n*16);
  float acc = b[0];
  #pragma unroll
  for (int q = 0; q < 4; ++q) {
    float4 t = fp[q];
    acc += t.x*w[q*4] + t.y*w[q*4+1] + t.z*w[q*4+2] + t.w*w[q*4+3];
  }
  out[n] = acc;
}

extern "C" void kernel_launch(void* const* d_in, const int* in_sizes, int n_in,
                              void* d_out, int out_size, void* d_ws, size_t ws_size,
                              hipStream_t stream) {
  const float* x     = (const float*)d_in[0];
  const void*  ei    = d_in[1];
  const float* ea    = (const float*)d_in[2];
  const float* fc1w  = (const float*)d_in[3];
  const float* fc1b  = (const float*)d_in[4];
  const float* k1w   = (const float*)d_in[5];
  const float* k1b   = (const float*)d_in[6];
  const float* k2w   = (const float*)d_in[7];
  const float* k2b   = (const float*)d_in[8];
  const float* k3w   = (const float*)d_in[9];
  const float* k3b   = (const float*)d_in[10];
  const float* rootw = (const float*)d_in[11];
  const float* convb = (const float*)d_in[12];
  const float* fc2w  = (const float*)d_in[13];
  const float* fc2b  = (const float*)d_in[14];
  int N = in_sizes[0];
  int E = in_sizes[1] / 2;

  char* base = (char*)d_ws;
  size_t off = 0;
  auto alloc = [&](size_t bytes) -> void* {
    void* p = base + off;
    off = (off + bytes + 255) & ~(size_t)255;
    return p;
  };
  int*      idx    = (int*)alloc((size_t)2*E*sizeof(int));
  int*      flag   = (int*)alloc(256);
  int*      rowptr = (int*)alloc((size_t)(N+1)*sizeof(int));
  int*      rowcur = (int*)alloc((size_t)N*sizeof(int));
  int*      bsum   = (int*)alloc(1024*sizeof(int));
  int*      eid    = (int*)alloc((size_t)E*sizeof(int));
  int*      srcS   = (int*)alloc((size_t)E*sizeof(int));
  float*    fA     = (float*)alloc((size_t)N*16*sizeof(float));
  float*    fB     = (float*)alloc((size_t)N*16*sizeof(float));
  float*    msg    = (float*)alloc((size_t)E*16*sizeof(float));
  uint16_t* w2t    = (uint16_t*)alloc(16384*2);
  uint16_t* w3t    = (uint16_t*)alloc(32768*2);
  if (off > ws_size) return;

  long long avail = (long long)ws_size - (long long)off;
  long long fullBytes = (long long)E * 256;
  int chunkE;
  if (avail >= fullBytes) {
    chunkE = E;
  } else {
    chunkE = (int)((avail / 256) & ~511LL);
    if (chunkE < 512) chunkE = 512;
  }
  uint16_t* h2 = (uint16_t*)alloc((size_t)chunkE * 256);
  bool full = (chunkE >= E);

  int* srcI = idx;
  int* dstI = idx + E;

  int n64 = E < 1024 ? E : 1024;
  k_detect<<<1, 256, 0, stream>>>((const long long*)ei, n64, (long long)N, flag);
  k_convert<<<(2*E + 255)/256, 256, 0, stream>>>(ei, 2*E, flag, idx);

  int nbN = (N + 255) / 256;
  k_zeroi<<<nbN, 256, 0, stream>>>(rowcur, N);
  k_count<<<(E + 255)/256, 256, 0, stream>>>(dstI, E, rowcur);
  k_scan1<<<nbN, 256, 0, stream>>>(rowcur, N, rowptr, bsum);
  k_scan2<<<1, 64, 0, stream>>>(bsum, nbN);
  k_scan3<<<nbN, 256, 0, stream>>>(rowptr, bsum, N, E);
  k_copyi<<<nbN, 256, 0, stream>>>(rowptr, rowcur, N);
  k_scatter<<<(E + 255)/256, 256, 0, stream>>>(srcI, dstI, E, rowcur, eid, srcS);

  k_prep<<<128, 256, 0, stream>>>(k2w, k3w, w2t, w3t);
  k_feat0<<<(N + 255)/256, 256, 0, stream>>>(x, fc1w, fc1b, fA, N);
  if (full)
    k_mlp12<<<(E + 255)/256, 512, 0, stream>>>(ea, eid, k1w, k1b, w2t, k2b, h2, 0, E);

  float* fin = fA;
  float* fout = fB;
  int nbAgg = (N + 15) / 16;
  for (int d = 0; d < 4; ++d) {
    if (full) {
      k_fused<<<(E + 255)/256, 512, 0, stream>>>(h2, w3t, k3b, fin, srcS, msg, 0, E);
    } else {
      for (int i0 = 0; i0 < E; i0 += chunkE) {
        int i1 = i0 + chunkE < E ? i0 + chunkE : E;
        k_mlp12<<<(i1 - i0 + 255)/256, 512, 0, stream>>>(ea, eid, k1w, k1b, w2t, k2b, h2, i0, i1);
        k_fused<<<(i1 - i0 + 255)/256, 512, 0, stream>>>(h2, w3t, k3b, fin, srcS, msg, i0, i1);
      }
    }
    k_agg<<<nbAgg, 256, 0, stream>>>(msg, rowptr, fin, rootw, convb, fout, N);
    float* t = fin; fin = fout; fout = t;
  }
  k_out<<<(N + 255)/256, 256, 0, stream>>>(fin, fc2w, fc2b, (float*)d_out, N);
}